// Round 1
// baseline (268.796 us; speedup 1.0000x reference)
//
#include <hip/hip_runtime.h>
#include <hip/hip_bf16.h>
#include <stdint.h>

typedef __bf16 bf16;
typedef __attribute__((ext_vector_type(8))) __bf16 bf16x8;
typedef __attribute__((ext_vector_type(4))) float f32x4;
typedef __attribute__((ext_vector_type(4))) unsigned int u32x4;

#define BATCH  2
#define SEQ    2048
#define DMODEL 1024
#define NH     16
#define DKH    64
#define BS     (BATCH*SEQ)        // 4096
#define BSD    (BS*DMODEL)        // 4194304 elems
#define DD     (DMODEL*DMODEL)    // 1048576 elems

__device__ __forceinline__ void gload_lds16(const bf16* g, bf16* l) {
  __builtin_amdgcn_global_load_lds((const __attribute__((address_space(1))) void*)g,
                                   (__attribute__((address_space(3))) void*)l,
                                   16, 0, 0);
}

// ---------------- fp32 -> bf16 convert (8 elems/thread) ----------------
__global__ __launch_bounds__(256) void cvt_kernel(const float* __restrict__ in,
                                                  bf16* __restrict__ out, int n8) {
  int i = blockIdx.x * blockDim.x + threadIdx.x;
  if (i >= n8) return;
  const f32x4* p = (const f32x4*)in + (size_t)i * 2;
  f32x4 a = p[0], b = p[1];
  bf16x8 o;
  o[0]=(bf16)a[0]; o[1]=(bf16)a[1]; o[2]=(bf16)a[2]; o[3]=(bf16)a[3];
  o[4]=(bf16)b[0]; o[5]=(bf16)b[1]; o[6]=(bf16)b[2]; o[7]=(bf16)b[3];
  ((bf16x8*)out)[i] = o;
}

// ---------------- GEMM: C[M,N] = A[M,K] @ W[N,K]^T + bias ----------------
// m97 structure: 128x128 tile, BK=32, 4 waves (2x2 of 64x64), global_load_lds w=16.
template <typename OUT>
__device__ __forceinline__ void gemm_body(const bf16* __restrict__ A,
                                          const bf16* __restrict__ W,
                                          const float* __restrict__ bias,
                                          OUT* __restrict__ C,
                                          int N, int K,
                                          bf16* Als, bf16* Bls) {
  const int tid  = threadIdx.x;
  const int lane = tid & 63;
  const int wave = tid >> 6;
  const int wm = wave >> 1, wn = wave & 1;
  const int c = lane & 15, g = lane >> 4;
  const long brow = (long)blockIdx.y * 128;
  const long bcol = (long)blockIdx.x * 128;

  f32x4 acc[4][4] = {};

  // staging: thread t, issue i: row = wave*16 + t/4 + i*64, col bytes = (t%4)*16
  const bf16* Ag = A + (brow + wave*16 + ((lane>>2)&15)) * (long)K + (lane & 3) * 8;
  const bf16* Bg = W + (bcol + wave*16 + ((lane>>2)&15)) * (long)K + (lane & 3) * 8;
  bf16* AlsW = Als + wave * 512;   // 64 lanes * 16B = 1KB = 512 bf16 per wave per issue
  bf16* BlsW = Bls + wave * 512;

  const int nk = K >> 5;
  for (int kt = 0; kt < nk; ++kt) {
    const bf16* a0 = Ag + kt * 32;
    const bf16* b0 = Bg + kt * 32;
    gload_lds16(a0,                AlsW);
    gload_lds16(a0 + 64 * (long)K, AlsW + 2048);
    gload_lds16(b0,                BlsW);
    gload_lds16(b0 + 64 * (long)K, BlsW + 2048);
    __syncthreads();   // drains vmcnt: LDS tiles ready

    bf16x8 af[4], bfv[4];
    #pragma unroll
    for (int m = 0; m < 4; ++m)
      af[m] = *(const bf16x8*)(Als + (wm*64 + m*16 + c) * 32 + g * 8);
    #pragma unroll
    for (int n = 0; n < 4; ++n)
      bfv[n] = *(const bf16x8*)(Bls + (wn*64 + n*16 + c) * 32 + g * 8);
    #pragma unroll
    for (int m = 0; m < 4; ++m)
      #pragma unroll
      for (int n = 0; n < 4; ++n)
        acc[m][n] = __builtin_amdgcn_mfma_f32_16x16x32_bf16(af[m], bfv[n], acc[m][n], 0, 0, 0);
    __syncthreads();   // all waves done reading before next stage overwrites
  }

  #pragma unroll
  for (int n = 0; n < 4; ++n) {
    const long col = bcol + wn*64 + n*16 + c;
    const float bb = bias[col];
    #pragma unroll
    for (int m = 0; m < 4; ++m) {
      #pragma unroll
      for (int r = 0; r < 4; ++r) {
        const long row = brow + wm*64 + m*16 + g*4 + r;  // C/D map: col=lane&15, row=(lane>>4)*4+r
        C[row * (long)N + col] = (OUT)(acc[m][n][r] + bb);
      }
    }
  }
}

__global__ __launch_bounds__(256) void gemm_qkv_kernel(
    const bf16* __restrict__ qb, const bf16* __restrict__ kb, const bf16* __restrict__ vb,
    const bf16* __restrict__ Wqb, const bf16* __restrict__ Wkb, const bf16* __restrict__ Wvb,
    const float* __restrict__ bq, const float* __restrict__ bk, const float* __restrict__ bv,
    bf16* __restrict__ qh, bf16* __restrict__ kh, bf16* __restrict__ vh) {
  __shared__ bf16 Als[128 * 32];
  __shared__ bf16 Bls[128 * 32];
  const int z = blockIdx.z;
  const bf16*  A  = (z == 0) ? qb  : (z == 1) ? kb  : vb;
  const bf16*  W  = (z == 0) ? Wqb : (z == 1) ? Wkb : Wvb;
  const float* bi = (z == 0) ? bq  : (z == 1) ? bk  : bv;
  bf16*        Cp = (z == 0) ? qh  : (z == 1) ? kh  : vh;
  gemm_body<bf16>(A, W, bi, Cp, DMODEL, DMODEL, Als, Bls);
}

__global__ __launch_bounds__(256) void gemm_out_kernel(
    const bf16* __restrict__ A, const bf16* __restrict__ Wob,
    const float* __restrict__ bo, float* __restrict__ C) {
  __shared__ bf16 Als[128 * 32];
  __shared__ bf16 Bls[128 * 32];
  gemm_body<float>(A, Wob, bo, C, DMODEL, DMODEL, Als, Bls);
}

// ---------------- Flash attention ----------------
// block = 4 waves; wave w owns q rows [q0 + w*16, +16); KV tiles of 64.
// K_lds & P_lds XOR-swizzled (row stride 128B is the pathological G4 case).
__global__ __launch_bounds__(256) void attn_kernel(const bf16* __restrict__ qh,
                                                   const bf16* __restrict__ kh,
                                                   const bf16* __restrict__ vh,
                                                   bf16* __restrict__ ao) {
  __shared__ bf16 Kls[64 * 64];
  __shared__ bf16 Vt [64 * 64];
  __shared__ bf16 Pls[4 * 16 * 64];

  const int tid = threadIdx.x;
  const int lane = tid & 63, wave = tid >> 6;
  const int c = lane & 15, g = lane >> 4;
  const int qt = blockIdx.x;          // 0..31 q-tiles
  const int bh = blockIdx.y;          // 0..31 (b,h)
  const int b = bh >> 4, h = bh & 15;
  const long rowbase = (long)b * SEQ;
  const int q0 = qt * 64;

  // Q fragments (A-operand: lane holds Q[q=c][dk=g*8+j (+32)])
  const bf16* qp = qh + (rowbase + q0 + wave*16 + c) * DMODEL + h * 64 + g * 8;
  bf16x8 qf0 = *(const bf16x8*)qp;
  bf16x8 qf1 = *(const bf16x8*)(qp + 32);

  f32x4 oacc[4] = {};
  float mrow[4] = {-1e30f, -1e30f, -1e30f, -1e30f};
  float lrow[4] = {};

  char* Kb = (char*)Kls;
  char* Vb = (char*)Vt;
  char* Pb = (char*)Pls + wave * 2048;

  for (int kv0 = 0; kv0 < SEQ; kv0 += 64) {
    // ---- stage K (swizzled) and V^T ----
    #pragma unroll
    for (int u = 0; u < 2; ++u) {
      int idx = u * 256 + tid;
      int r = idx >> 3, c8 = idx & 7;
      const bf16* ksrc = kh + (rowbase + kv0 + r) * DMODEL + h * 64 + c8 * 8;
      u32x4 d = *(const u32x4*)ksrc;
      *(u32x4*)(Kb + r * 128 + ((c8 * 16) ^ ((r & 7) << 4))) = d;
      const bf16* vsrc = vh + (rowbase + kv0 + r) * DMODEL + h * 64 + c8 * 8;
      u32x4 dv = *(const u32x4*)vsrc;
      const bf16* e = (const bf16*)&dv;
      #pragma unroll
      for (int j = 0; j < 8; ++j) {
        int drow = c8 * 8 + j;     // Vt[d][kv], swizzled
        *(bf16*)(Vb + drow * 128 + ((r * 2) ^ ((drow & 7) << 4))) = e[j];
      }
    }
    __syncthreads();

    // ---- QK^T: scores[16q x 64kv] per wave ----
    f32x4 sc[4] = {};
    #pragma unroll
    for (int n = 0; n < 4; ++n) {
      int krow = n * 16 + c;
      bf16x8 kb0 = *(const bf16x8*)(Kb + krow * 128 + ((g * 16     ) ^ ((krow & 7) << 4)));
      bf16x8 kb1 = *(const bf16x8*)(Kb + krow * 128 + ((g * 16 + 64) ^ ((krow & 7) << 4)));
      sc[n] = __builtin_amdgcn_mfma_f32_16x16x32_bf16(qf0, kb0, sc[n], 0, 0, 0);
      sc[n] = __builtin_amdgcn_mfma_f32_16x16x32_bf16(qf1, kb1, sc[n], 0, 0, 0);
    }

    // ---- online softmax (row = g*4+r; reduce over 4 frags + 16 lanes) ----
    #pragma unroll
    for (int r = 0; r < 4; ++r) {
      float mt = -1e30f;
      #pragma unroll
      for (int n = 0; n < 4; ++n) { sc[n][r] *= 0.125f; mt = fmaxf(mt, sc[n][r]); }
      mt = fmaxf(mt, __shfl_xor(mt, 1));
      mt = fmaxf(mt, __shfl_xor(mt, 2));
      mt = fmaxf(mt, __shfl_xor(mt, 4));
      mt = fmaxf(mt, __shfl_xor(mt, 8));
      float mnew = fmaxf(mrow[r], mt);
      float alpha = __expf(mrow[r] - mnew);
      mrow[r] = mnew;
      float ps = 0.f;
      #pragma unroll
      for (int n = 0; n < 4; ++n) { float p = __expf(sc[n][r] - mnew); sc[n][r] = p; ps += p; }
      ps += __shfl_xor(ps, 1);
      ps += __shfl_xor(ps, 2);
      ps += __shfl_xor(ps, 4);
      ps += __shfl_xor(ps, 8);
      lrow[r] = lrow[r] * alpha + ps;
      #pragma unroll
      for (int n = 0; n < 4; ++n) oacc[n][r] *= alpha;
    }

    // ---- write P (bf16) to per-wave LDS (swizzled) ----
    #pragma unroll
    for (int r = 0; r < 4; ++r) {
      int prow = g * 4 + r;
      #pragma unroll
      for (int n = 0; n < 4; ++n) {
        int pcol = (c + n * 16) * 2;
        *(bf16*)(Pb + prow * 128 + (pcol ^ ((prow & 7) << 4))) = (bf16)sc[n][r];
      }
    }

    // ---- PV: oacc[16q x 64d] += P @ V ----
    #pragma unroll
    for (int ks = 0; ks < 2; ++ks) {
      bf16x8 pa = *(const bf16x8*)(Pb + c * 128 + ((g * 16 + ks * 64) ^ ((c & 7) << 4)));
      #pragma unroll
      for (int n = 0; n < 4; ++n) {
        int vrow = n * 16 + c;
        bf16x8 vb = *(const bf16x8*)(Vb + vrow * 128 + ((g * 16 + ks * 64) ^ ((vrow & 7) << 4)));
        oacc[n] = __builtin_amdgcn_mfma_f32_16x16x32_bf16(pa, vb, oacc[n], 0, 0, 0);
      }
    }
    __syncthreads();
  }

  // ---- epilogue: O / l -> attn-out [B*S, D] ----
  float inv[4];
  #pragma unroll
  for (int r = 0; r < 4; ++r) inv[r] = 1.f / lrow[r];
  #pragma unroll
  for (int r = 0; r < 4; ++r) {
    long row = rowbase + q0 + wave * 16 + g * 4 + r;
    bf16* dst = ao + row * DMODEL + h * 64 + c;
    #pragma unroll
    for (int n = 0; n < 4; ++n) dst[n * 16] = (bf16)(oacc[n][r] * inv[r]);
  }
}

// ---------------- host ----------------
extern "C" void kernel_launch(void* const* d_in, const int* in_sizes, int n_in,
                              void* d_out, int out_size, void* d_ws, size_t ws_size,
                              hipStream_t stream) {
  const float* q  = (const float*)d_in[0];
  const float* k  = (const float*)d_in[1];
  const float* v  = (const float*)d_in[2];
  const float* Wq = (const float*)d_in[3];
  const float* bq = (const float*)d_in[4];
  const float* Wk = (const float*)d_in[5];
  const float* bk = (const float*)d_in[6];
  const float* Wv = (const float*)d_in[7];
  const float* bv = (const float*)d_in[8];
  const float* Wo = (const float*)d_in[9];
  const float* bo = (const float*)d_in[10];
  float* out = (float*)d_out;

  char* w = (char*)d_ws;
  bf16* qb  = (bf16*)w; w += (size_t)BSD * 2;
  bf16* kb  = (bf16*)w; w += (size_t)BSD * 2;
  bf16* vb  = (bf16*)w; w += (size_t)BSD * 2;
  bf16* Wqb = (bf16*)w; w += (size_t)DD * 2;
  bf16* Wkb = (bf16*)w; w += (size_t)DD * 2;
  bf16* Wvb = (bf16*)w; w += (size_t)DD * 2;
  bf16* Wob = (bf16*)w; w += (size_t)DD * 2;
  bf16* qhd = (bf16*)w; w += (size_t)BSD * 2;
  bf16* khd = (bf16*)w; w += (size_t)BSD * 2;
  bf16* vhd = (bf16*)w; w += (size_t)BSD * 2;
  bf16* aod = (bf16*)w; w += (size_t)BSD * 2;   // 64 MB total

  // converts
  cvt_kernel<<<BSD / 8 / 256, 256, 0, stream>>>(q, qb, BSD / 8);
  cvt_kernel<<<BSD / 8 / 256, 256, 0, stream>>>(k, kb, BSD / 8);
  cvt_kernel<<<BSD / 8 / 256, 256, 0, stream>>>(v, vb, BSD / 8);
  cvt_kernel<<<DD  / 8 / 256, 256, 0, stream>>>(Wq, Wqb, DD / 8);
  cvt_kernel<<<DD  / 8 / 256, 256, 0, stream>>>(Wk, Wkb, DD / 8);
  cvt_kernel<<<DD  / 8 / 256, 256, 0, stream>>>(Wv, Wvb, DD / 8);
  cvt_kernel<<<DD  / 8 / 256, 256, 0, stream>>>(Wo, Wob, DD / 8);

  // QKV projections: grid (N/128=8, M/128=32, 3)
  gemm_qkv_kernel<<<dim3(8, 32, 3), 256, 0, stream>>>(qb, kb, vb, Wqb, Wkb, Wvb,
                                                      bq, bk, bv, qhd, khd, vhd);
  // attention: grid (q-tiles=32, b*h=32)
  attn_kernel<<<dim3(32, 32), 256, 0, stream>>>(qhd, khd, vhd, aod);
  // output projection
  gemm_out_kernel<<<dim3(8, 32), 256, 0, stream>>>(aod, Wob, bo, out);
}

// Round 2
// 189.163 us; speedup vs baseline: 1.4210x; 1.4210x over previous
//
#include <hip/hip_runtime.h>
#include <hip/hip_bf16.h>
#include <stdint.h>

typedef __bf16 bf16;
typedef __attribute__((ext_vector_type(8))) __bf16 bf16x8;
typedef __attribute__((ext_vector_type(4))) float f32x4;
typedef __attribute__((ext_vector_type(4))) unsigned int u32x4;
typedef __attribute__((ext_vector_type(2))) unsigned int u32x2;

#define BATCH  2
#define SEQ    2048
#define DMODEL 1024
#define NH     16
#define DKH    64
#define BS     (BATCH*SEQ)        // 4096
#define BSD    (BS*DMODEL)        // 4194304 elems
#define DD     (DMODEL*DMODEL)    // 1048576 elems

__device__ __forceinline__ void gload_lds16(const bf16* g, bf16* l) {
  __builtin_amdgcn_global_load_lds((const __attribute__((address_space(1))) void*)g,
                                   (__attribute__((address_space(3))) void*)l,
                                   16, 0, 0);
}

__device__ __forceinline__ unsigned int packbf2(float a, float b) {
  union { bf16 h[2]; unsigned int u; } z;
  z.h[0] = (bf16)a; z.h[1] = (bf16)b;
  return z.u;
}

// ---------------- fp32 -> bf16 convert (8 elems/thread) ----------------
__global__ __launch_bounds__(256) void cvt_kernel(const float* __restrict__ in,
                                                  bf16* __restrict__ out, int n8) {
  int i = blockIdx.x * blockDim.x + threadIdx.x;
  if (i >= n8) return;
  const f32x4* p = (const f32x4*)in + (size_t)i * 2;
  f32x4 a = p[0], b = p[1];
  bf16x8 o;
  o[0]=(bf16)a[0]; o[1]=(bf16)a[1]; o[2]=(bf16)a[2]; o[3]=(bf16)a[3];
  o[4]=(bf16)b[0]; o[5]=(bf16)b[1]; o[6]=(bf16)b[2]; o[7]=(bf16)b[3];
  ((bf16x8*)out)[i] = o;
}

// ---------------- GEMM: C = A[M,K] @ W[N,K]^T + bias ----------------
// m97 structure: 128x128 tile, BK=32, 4 waves (2x2 of 64x64), global_load_lds w=16.
// MODE 0: row-major C[M,N] (scaled). MODE 1: per-head transposed write into
//         vt[(b*16+h)*64+dk][2048] (for attention's V^T operand).
template <typename OUT, int MODE>
__device__ __forceinline__ void gemm_body(const bf16* __restrict__ A,
                                          const bf16* __restrict__ W,
                                          const float* __restrict__ bias,
                                          OUT* __restrict__ C,
                                          float oscale,
                                          bf16* Als, bf16* Bls) {
  const int tid  = threadIdx.x;
  const int lane = tid & 63;
  const int wave = tid >> 6;
  const int wm = wave >> 1, wn = wave & 1;
  const int c = lane & 15, g = lane >> 4;
  const long brow = (long)blockIdx.y * 128;
  const long bcol = (long)blockIdx.x * 128;
  const int  N = DMODEL, K = DMODEL;

  f32x4 acc[4][4] = {};

  const bf16* Ag = A + (brow + wave*16 + ((lane>>2)&15)) * (long)K + (lane & 3) * 8;
  const bf16* Bg = W + (bcol + wave*16 + ((lane>>2)&15)) * (long)K + (lane & 3) * 8;
  bf16* AlsW = Als + wave * 512;
  bf16* BlsW = Bls + wave * 512;

  const int nk = K >> 5;
  for (int kt = 0; kt < nk; ++kt) {
    const bf16* a0 = Ag + kt * 32;
    const bf16* b0 = Bg + kt * 32;
    gload_lds16(a0,                AlsW);
    gload_lds16(a0 + 64 * (long)K, AlsW + 2048);
    gload_lds16(b0,                BlsW);
    gload_lds16(b0 + 64 * (long)K, BlsW + 2048);
    __syncthreads();

    bf16x8 af[4], bfv[4];
    #pragma unroll
    for (int m = 0; m < 4; ++m)
      af[m] = *(const bf16x8*)(Als + (wm*64 + m*16 + c) * 32 + g * 8);
    #pragma unroll
    for (int n = 0; n < 4; ++n)
      bfv[n] = *(const bf16x8*)(Bls + (wn*64 + n*16 + c) * 32 + g * 8);
    #pragma unroll
    for (int m = 0; m < 4; ++m)
      #pragma unroll
      for (int n = 0; n < 4; ++n)
        acc[m][n] = __builtin_amdgcn_mfma_f32_16x16x32_bf16(af[m], bfv[n], acc[m][n], 0, 0, 0);
    __syncthreads();
  }

  if (MODE == 0) {
    #pragma unroll
    for (int n = 0; n < 4; ++n) {
      const long col = bcol + wn*64 + n*16 + c;
      const float bb = bias[col];
      #pragma unroll
      for (int m = 0; m < 4; ++m) {
        #pragma unroll
        for (int r = 0; r < 4; ++r) {
          const long row = brow + wm*64 + m*16 + g*4 + r;
          C[row * (long)N + col] = (OUT)((acc[m][n][r] + bb) * oscale);
        }
      }
    }
  } else {
    // transposed per-head write: vt[((b*16+h)*64 + dk)*2048 + s]
    const int srow = (int)(brow & (SEQ - 1));
    const int bidx = (int)(brow >> 11);
    #pragma unroll
    for (int n = 0; n < 4; ++n) {
      const int col = (int)bcol + wn*64 + n*16 + c;   // d in [0,1024)
      const float bb = bias[col];
      const int h = col >> 6, dk = col & 63;
      OUT* rowp = C + ((size_t)((bidx*16 + h)*64 + dk)) * SEQ + srow + wm*64;
      #pragma unroll
      for (int m = 0; m < 4; ++m) {
        u32x2 pkd;
        pkd[0] = packbf2(acc[m][n][0] + bb, acc[m][n][1] + bb);
        pkd[1] = packbf2(acc[m][n][2] + bb, acc[m][n][3] + bb);
        *(u32x2*)(rowp + m*16 + g*4) = pkd;
      }
    }
  }
}

__global__ __launch_bounds__(256) void gemm_qk_kernel(
    const bf16* __restrict__ qb, const bf16* __restrict__ kb,
    const bf16* __restrict__ Wqb, const bf16* __restrict__ Wkb,
    const float* __restrict__ bq, const float* __restrict__ bk,
    bf16* __restrict__ qh, bf16* __restrict__ kh) {
  __shared__ bf16 Als[128 * 32];
  __shared__ bf16 Bls[128 * 32];
  const int z = blockIdx.z;
  const bf16*  A  = (z == 0) ? qb  : kb;
  const bf16*  W  = (z == 0) ? Wqb : Wkb;
  const float* bi = (z == 0) ? bq  : bk;
  bf16*        Cp = (z == 0) ? qh  : kh;
  const float  os = (z == 0) ? 0.125f : 1.0f;   // fold 1/sqrt(DK) into Q
  gemm_body<bf16, 0>(A, W, bi, Cp, os, Als, Bls);
}

__global__ __launch_bounds__(256) void gemm_v_kernel(
    const bf16* __restrict__ vb, const bf16* __restrict__ Wvb,
    const float* __restrict__ bv, bf16* __restrict__ vt) {
  __shared__ bf16 Als[128 * 32];
  __shared__ bf16 Bls[128 * 32];
  gemm_body<bf16, 1>(vb, Wvb, bv, vt, 1.0f, Als, Bls);
}

__global__ __launch_bounds__(256) void gemm_out_kernel(
    const bf16* __restrict__ A, const bf16* __restrict__ Wob,
    const float* __restrict__ bo, float* __restrict__ C) {
  __shared__ bf16 Als[128 * 32];
  __shared__ bf16 Bls[128 * 32];
  gemm_body<float, 0>(A, Wob, bo, C, 1.0f, Als, Bls);
}

// ---------------- Flash attention (swapped QK^T, in-register P^T) ----------------
// 4 waves, 16 q-rows each. K and V^T staged row-major 64x64, XOR-swizzled,
// double-buffered (1 barrier/tile, T14 async-stage split).
__global__ __launch_bounds__(256) void attn_kernel(const bf16* __restrict__ qh,
                                                   const bf16* __restrict__ kh,
                                                   const bf16* __restrict__ vt,
                                                   bf16* __restrict__ ao) {
  __shared__ bf16 Kls[2][64 * 64];
  __shared__ bf16 Vls[2][64 * 64];

  const int tid = threadIdx.x;
  const int lane = tid & 63, wave = tid >> 6;
  const int c = lane & 15, g = lane >> 4;

  // bijective XCD swizzle: 4 heads per XCD -> K/V slice (2MB) fits per-XCD L2
  const int bx  = blockIdx.x;
  const int bh  = (bx & 7) * 4 + ((bx >> 3) >> 5);
  const int qt  = (bx >> 3) & 31;
  const int b = bh >> 4, h = bh & 15;
  const long rowbase = (long)b * SEQ;
  const int q0 = qt * 64;

  // Q fragments (B-operand: lane holds Q[q=c][dk=g*8+j])
  const bf16* qp = qh + (rowbase + q0 + wave*16 + c) * DMODEL + h * 64 + g * 8;
  bf16x8 qf0 = *(const bf16x8*)qp;
  bf16x8 qf1 = *(const bf16x8*)(qp + 32);

  f32x4 oacc[4] = {};                 // O^T[d = m4*16+g*4+r][q=c]
  float mrun = -1e30f, lrun = 0.f;

  // staging: thread covers rows (tid>>3) and (tid>>3)+32, 16B chunk (tid&7)
  const int srw = tid >> 3, stc = tid & 7;
  u32x4 kreg0, kreg1, vreg0, vreg1;

  auto load_tiles = [&](int kv0) {
    const bf16* kp = kh + (rowbase + kv0 + srw) * DMODEL + h * 64 + stc * 8;
    kreg0 = *(const u32x4*)kp;
    kreg1 = *(const u32x4*)(kp + 32 * DMODEL);
    const bf16* vp = vt + ((size_t)bh * 64 + srw) * SEQ + kv0 + stc * 8;
    vreg0 = *(const u32x4*)vp;
    vreg1 = *(const u32x4*)(vp + 32 * SEQ);
  };
  auto write_tiles = [&](int buf) {
    char* Kb = (char*)Kls[buf];
    char* Vb = (char*)Vls[buf];
    const int off0 = srw * 128 + ((stc * 16) ^ ((srw & 7) << 4));
    *(u32x4*)(Kb + off0)        = kreg0;
    *(u32x4*)(Kb + off0 + 4096) = kreg1;   // row+32: same &7 -> same swizzle
    *(u32x4*)(Vb + off0)        = vreg0;
    *(u32x4*)(Vb + off0 + 4096) = vreg1;
  };

  load_tiles(0);
  write_tiles(0);
  int cur = 0;
  const int NT = SEQ / 64;

  for (int t = 0; t < NT; ++t) {
    __syncthreads();                       // LDS[cur] ready; LDS[cur^1] free
    if (t + 1 < NT) load_tiles((t + 1) * 64);

    const char* Kb = (const char*)Kls[cur];
    const char* Vb = (const char*)Vls[cur];

    // ---- QK^T swapped: s[n][r] = S^T[kv = n*16+g*4+r][q = c] ----
    f32x4 s[4] = {};
    #pragma unroll
    for (int n = 0; n < 4; ++n) {
      const int row = n * 16 + c;
      const int sw = (row & 7) << 4;
      bf16x8 k0 = *(const bf16x8*)(Kb + row * 128 + ((g * 16     ) ^ sw));
      bf16x8 k1 = *(const bf16x8*)(Kb + row * 128 + ((g * 16 + 64) ^ sw));
      s[n] = __builtin_amdgcn_mfma_f32_16x16x32_bf16(k0, qf0, s[n], 0, 0, 0);
      s[n] = __builtin_amdgcn_mfma_f32_16x16x32_bf16(k1, qf1, s[n], 0, 0, 0);
    }

    // ---- online softmax over kv (in-lane 16 + 2 shfls across g) ----
    float mt = s[0][0];
    #pragma unroll
    for (int n = 0; n < 4; ++n)
      #pragma unroll
      for (int r = 0; r < 4; ++r) mt = fmaxf(mt, s[n][r]);
    mt = fmaxf(mt, __shfl_xor(mt, 16));
    mt = fmaxf(mt, __shfl_xor(mt, 32));
    const float mnew = fmaxf(mrun, mt);
    const float alpha = __expf(mrun - mnew);
    mrun = mnew;
    float ps = 0.f;
    #pragma unroll
    for (int n = 0; n < 4; ++n)
      #pragma unroll
      for (int r = 0; r < 4; ++r) {
        float p = __expf(s[n][r] - mnew);
        s[n][r] = p; ps += p;
      }
    ps += __shfl_xor(ps, 16);
    ps += __shfl_xor(ps, 32);
    lrun = lrun * alpha + ps;
    #pragma unroll
    for (int m4 = 0; m4 < 4; ++m4) oacc[m4] *= alpha;

    // ---- pack P^T to bf16 pairs: pk[n][rp] = (kv=n*16+g*4+2rp, +1) @ q=c ----
    unsigned int pk[4][2];
    #pragma unroll
    for (int n = 0; n < 4; ++n) {
      pk[n][0] = packbf2(s[n][0], s[n][1]);
      pk[n][1] = packbf2(s[n][2], s[n][3]);
    }

    // ---- assemble PV B-operand: lane (c,g) needs P^T[kv=ks*32+g*8+j][q=c] ----
    union U8 { unsigned int u[4]; bf16x8 v; } pf0, pf1;
    const int base = c + 32 * (g & 1);
    const int sel = g >> 1;
    #pragma unroll
    for (int w = 0; w < 4; ++w) {
      const int sl = base + 16 * (w >> 1);
      unsigned int a0 = (unsigned int)__shfl((int)pk[0][w & 1], sl);
      unsigned int a1 = (unsigned int)__shfl((int)pk[1][w & 1], sl);
      pf0.u[w] = sel ? a1 : a0;
      unsigned int b0 = (unsigned int)__shfl((int)pk[2][w & 1], sl);
      unsigned int b1 = (unsigned int)__shfl((int)pk[3][w & 1], sl);
      pf1.u[w] = sel ? b1 : b0;
    }

    // ---- PV: O^T[d][q] += V^T[d][kv] * P^T[kv][q] ----
    #pragma unroll
    for (int m4 = 0; m4 < 4; ++m4) {
      const int row = m4 * 16 + c;
      const int sw = (row & 7) << 4;
      bf16x8 v0 = *(const bf16x8*)(Vb + row * 128 + ((g * 16     ) ^ sw));
      bf16x8 v1 = *(const bf16x8*)(Vb + row * 128 + ((g * 16 + 64) ^ sw));
      oacc[m4] = __builtin_amdgcn_mfma_f32_16x16x32_bf16(v0, pf0.v, oacc[m4], 0, 0, 0);
      oacc[m4] = __builtin_amdgcn_mfma_f32_16x16x32_bf16(v1, pf1.v, oacc[m4], 0, 0, 0);
    }

    if (t + 1 < NT) write_tiles(cur ^ 1);
    cur ^= 1;
  }

  // ---- epilogue: O^T/l -> ao[q][d], packed b64 stores ----
  const float inv = 1.f / lrun;
  bf16* dst = ao + (rowbase + q0 + wave * 16 + c) * DMODEL + h * 64;
  #pragma unroll
  for (int m4 = 0; m4 < 4; ++m4) {
    u32x2 pkd;
    pkd[0] = packbf2(oacc[m4][0] * inv, oacc[m4][1] * inv);
    pkd[1] = packbf2(oacc[m4][2] * inv, oacc[m4][3] * inv);
    *(u32x2*)(dst + m4 * 16 + g * 4) = pkd;
  }
}

// ---------------- host ----------------
extern "C" void kernel_launch(void* const* d_in, const int* in_sizes, int n_in,
                              void* d_out, int out_size, void* d_ws, size_t ws_size,
                              hipStream_t stream) {
  const float* q  = (const float*)d_in[0];
  const float* k  = (const float*)d_in[1];
  const float* v  = (const float*)d_in[2];
  const float* Wq = (const float*)d_in[3];
  const float* bq = (const float*)d_in[4];
  const float* Wk = (const float*)d_in[5];
  const float* bk = (const float*)d_in[6];
  const float* Wv = (const float*)d_in[7];
  const float* bv = (const float*)d_in[8];
  const float* Wo = (const float*)d_in[9];
  const float* bo = (const float*)d_in[10];
  float* out = (float*)d_out;

  char* w = (char*)d_ws;
  bf16* qb  = (bf16*)w; w += (size_t)BSD * 2;
  bf16* kb  = (bf16*)w; w += (size_t)BSD * 2;
  bf16* vb  = (bf16*)w; w += (size_t)BSD * 2;
  bf16* Wqb = (bf16*)w; w += (size_t)DD * 2;
  bf16* Wkb = (bf16*)w; w += (size_t)DD * 2;
  bf16* Wvb = (bf16*)w; w += (size_t)DD * 2;
  bf16* Wob = (bf16*)w; w += (size_t)DD * 2;
  bf16* qhd = (bf16*)w; w += (size_t)BSD * 2;
  bf16* khd = (bf16*)w; w += (size_t)BSD * 2;
  bf16* vtd = (bf16*)w; w += (size_t)BSD * 2;   // V^T: [(b*16+h)*64+dk][2048]
  bf16* aod = (bf16*)w; w += (size_t)BSD * 2;

  cvt_kernel<<<BSD / 8 / 256, 256, 0, stream>>>(q, qb, BSD / 8);
  cvt_kernel<<<BSD / 8 / 256, 256, 0, stream>>>(k, kb, BSD / 8);
  cvt_kernel<<<BSD / 8 / 256, 256, 0, stream>>>(v, vb, BSD / 8);
  cvt_kernel<<<DD  / 8 / 256, 256, 0, stream>>>(Wq, Wqb, DD / 8);
  cvt_kernel<<<DD  / 8 / 256, 256, 0, stream>>>(Wk, Wkb, DD / 8);
  cvt_kernel<<<DD  / 8 / 256, 256, 0, stream>>>(Wv, Wvb, DD / 8);
  cvt_kernel<<<DD  / 8 / 256, 256, 0, stream>>>(Wo, Wob, DD / 8);

  gemm_qk_kernel<<<dim3(8, 32, 2), 256, 0, stream>>>(qb, kb, Wqb, Wkb, bq, bk, qhd, khd);
  gemm_v_kernel<<<dim3(8, 32), 256, 0, stream>>>(vb, Wvb, bv, vtd);
  attn_kernel<<<1024, 256, 0, stream>>>(qhd, khd, vtd, aod);
  gemm_out_kernel<<<dim3(8, 32), 256, 0, stream>>>(aod, Wob, bo, out);
}

// Round 3
// 188.720 us; speedup vs baseline: 1.4243x; 1.0023x over previous
//
#include <hip/hip_runtime.h>
#include <hip/hip_bf16.h>
#include <stdint.h>

typedef __bf16 bf16;
typedef __attribute__((ext_vector_type(8))) __bf16 bf16x8;
typedef __attribute__((ext_vector_type(4))) float f32x4;
typedef __attribute__((ext_vector_type(4))) unsigned int u32x4;
typedef __attribute__((ext_vector_type(2))) unsigned int u32x2;

#define BATCH  2
#define SEQ    2048
#define DMODEL 1024
#define NH     16
#define DKH    64
#define BS     (BATCH*SEQ)        // 4096
#define BSD    (BS*DMODEL)        // 4194304 elems
#define DD     (DMODEL*DMODEL)    // 1048576 elems

__device__ __forceinline__ void gload_lds16(const bf16* g, bf16* l) {
  __builtin_amdgcn_global_load_lds((const __attribute__((address_space(1))) void*)g,
                                   (__attribute__((address_space(3))) void*)l,
                                   16, 0, 0);
}

__device__ __forceinline__ unsigned int packbf2(float a, float b) {
  union { bf16 h[2]; unsigned int u; } z;
  z.h[0] = (bf16)a; z.h[1] = (bf16)b;
  return z.u;
}

// ---------------- fp32 -> bf16 convert (8 elems/thread) ----------------
__global__ __launch_bounds__(256) void cvt_kernel(const float* __restrict__ in,
                                                  bf16* __restrict__ out, int n8) {
  int i = blockIdx.x * blockDim.x + threadIdx.x;
  if (i >= n8) return;
  const f32x4* p = (const f32x4*)in + (size_t)i * 2;
  f32x4 a = p[0], b = p[1];
  bf16x8 o;
  o[0]=(bf16)a[0]; o[1]=(bf16)a[1]; o[2]=(bf16)a[2]; o[3]=(bf16)a[3];
  o[4]=(bf16)b[0]; o[5]=(bf16)b[1]; o[6]=(bf16)b[2]; o[7]=(bf16)b[3];
  ((bf16x8*)out)[i] = o;
}

// ---------------- GEMM: C = A[M,K] @ W[N,K]^T + bias ----------------
// m97 structure: 128x128 tile, BK=32, 4 waves (2x2 of 64x64), global_load_lds w=16.
// MODE 0: row-major C[M,N] (scaled). MODE 1: per-head transposed write into
//         vt[(b*16+h)*64+dk][2048] (for attention's V^T operand).
template <typename OUT, int MODE>
__device__ __forceinline__ void gemm_body(const bf16* __restrict__ A,
                                          const bf16* __restrict__ W,
                                          const float* __restrict__ bias,
                                          OUT* __restrict__ C,
                                          float oscale,
                                          bf16* Als, bf16* Bls) {
  const int tid  = threadIdx.x;
  const int lane = tid & 63;
  const int wave = tid >> 6;
  const int wm = wave >> 1, wn = wave & 1;
  const int c = lane & 15, g = lane >> 4;
  const long brow = (long)blockIdx.y * 128;
  const long bcol = (long)blockIdx.x * 128;
  const int  N = DMODEL, K = DMODEL;

  f32x4 acc[4][4] = {};

  const bf16* Ag = A + (brow + wave*16 + ((lane>>2)&15)) * (long)K + (lane & 3) * 8;
  const bf16* Bg = W + (bcol + wave*16 + ((lane>>2)&15)) * (long)K + (lane & 3) * 8;
  bf16* AlsW = Als + wave * 512;
  bf16* BlsW = Bls + wave * 512;

  const int nk = K >> 5;
  for (int kt = 0; kt < nk; ++kt) {
    const bf16* a0 = Ag + kt * 32;
    const bf16* b0 = Bg + kt * 32;
    gload_lds16(a0,                AlsW);
    gload_lds16(a0 + 64 * (long)K, AlsW + 2048);
    gload_lds16(b0,                BlsW);
    gload_lds16(b0 + 64 * (long)K, BlsW + 2048);
    __syncthreads();

    bf16x8 af[4], bfv[4];
    #pragma unroll
    for (int m = 0; m < 4; ++m)
      af[m] = *(const bf16x8*)(Als + (wm*64 + m*16 + c) * 32 + g * 8);
    #pragma unroll
    for (int n = 0; n < 4; ++n)
      bfv[n] = *(const bf16x8*)(Bls + (wn*64 + n*16 + c) * 32 + g * 8);
    #pragma unroll
    for (int m = 0; m < 4; ++m)
      #pragma unroll
      for (int n = 0; n < 4; ++n)
        acc[m][n] = __builtin_amdgcn_mfma_f32_16x16x32_bf16(af[m], bfv[n], acc[m][n], 0, 0, 0);
    __syncthreads();
  }

  if (MODE == 0) {
    #pragma unroll
    for (int n = 0; n < 4; ++n) {
      const long col = bcol + wn*64 + n*16 + c;
      const float bb = bias[col];
      #pragma unroll
      for (int m = 0; m < 4; ++m) {
        #pragma unroll
        for (int r = 0; r < 4; ++r) {
          const long row = brow + wm*64 + m*16 + g*4 + r;
          C[row * (long)N + col] = (OUT)((acc[m][n][r] + bb) * oscale);
        }
      }
    }
  } else {
    // transposed per-head write: vt[((b*16+h)*64 + dk)*2048 + s]
    const int srow = (int)(brow & (SEQ - 1));
    const int bidx = (int)(brow >> 11);
    #pragma unroll
    for (int n = 0; n < 4; ++n) {
      const int col = (int)bcol + wn*64 + n*16 + c;   // d in [0,1024)
      const float bb = bias[col];
      const int h = col >> 6, dk = col & 63;
      OUT* rowp = C + ((size_t)((bidx*16 + h)*64 + dk)) * SEQ + srow + wm*64;
      #pragma unroll
      for (int m = 0; m < 4; ++m) {
        u32x2 pkd;
        pkd[0] = packbf2(acc[m][n][0] + bb, acc[m][n][1] + bb);
        pkd[1] = packbf2(acc[m][n][2] + bb, acc[m][n][3] + bb);
        *(u32x2*)(rowp + m*16 + g*4) = pkd;
      }
    }
  }
}

__global__ __launch_bounds__(256) void gemm_qk_kernel(
    const bf16* __restrict__ qb, const bf16* __restrict__ kb,
    const bf16* __restrict__ Wqb, const bf16* __restrict__ Wkb,
    const float* __restrict__ bq, const float* __restrict__ bk,
    bf16* __restrict__ qh, bf16* __restrict__ kh) {
  __shared__ bf16 Als[128 * 32];
  __shared__ bf16 Bls[128 * 32];
  const int z = blockIdx.z;
  const bf16*  A  = (z == 0) ? qb  : kb;
  const bf16*  W  = (z == 0) ? Wqb : Wkb;
  const float* bi = (z == 0) ? bq  : bk;
  bf16*        Cp = (z == 0) ? qh  : kh;
  const float  os = (z == 0) ? 0.125f : 1.0f;   // fold 1/sqrt(DK) into Q
  gemm_body<bf16, 0>(A, W, bi, Cp, os, Als, Bls);
}

__global__ __launch_bounds__(256) void gemm_v_kernel(
    const bf16* __restrict__ vb, const bf16* __restrict__ Wvb,
    const float* __restrict__ bv, bf16* __restrict__ vt) {
  __shared__ bf16 Als[128 * 32];
  __shared__ bf16 Bls[128 * 32];
  gemm_body<bf16, 1>(vb, Wvb, bv, vt, 1.0f, Als, Bls);
}

__global__ __launch_bounds__(256) void gemm_out_kernel(
    const bf16* __restrict__ A, const bf16* __restrict__ Wob,
    const float* __restrict__ bo, float* __restrict__ C) {
  __shared__ bf16 Als[128 * 32];
  __shared__ bf16 Bls[128 * 32];
  gemm_body<float, 0>(A, Wob, bo, C, 1.0f, Als, Bls);
}

// ---------------- Flash attention (swapped QK^T, in-register P^T) ----------------
// 4 waves, 16 q-rows each. K and V^T staged row-major 64x64, XOR-swizzled,
// double-buffered (1 barrier/tile, T14 async-stage split).
__global__ __launch_bounds__(256) void attn_kernel(const bf16* __restrict__ qh,
                                                   const bf16* __restrict__ kh,
                                                   const bf16* __restrict__ vt,
                                                   bf16* __restrict__ ao) {
  __shared__ bf16 Kls[2][64 * 64];
  __shared__ bf16 Vls[2][64 * 64];

  const int tid = threadIdx.x;
  const int lane = tid & 63, wave = tid >> 6;
  const int c = lane & 15, g = lane >> 4;

  // bijective XCD swizzle: 4 heads per XCD -> K/V slice (2MB) fits per-XCD L2
  const int bx  = blockIdx.x;
  const int bh  = (bx & 7) * 4 + ((bx >> 3) >> 5);
  const int qt  = (bx >> 3) & 31;
  const int b = bh >> 4, h = bh & 15;
  const long rowbase = (long)b * SEQ;
  const int q0 = qt * 64;

  // Q fragments (B-operand: lane holds Q[q=c][dk=g*8+j])
  const bf16* qp = qh + (rowbase + q0 + wave*16 + c) * DMODEL + h * 64 + g * 8;
  bf16x8 qf0 = *(const bf16x8*)qp;
  bf16x8 qf1 = *(const bf16x8*)(qp + 32);

  f32x4 oacc[4] = {};                 // O^T[d = m4*16+g*4+r][q=c]
  float mrun = -1e30f, lrun = 0.f;

  // staging: thread covers rows (tid>>3) and (tid>>3)+32, 16B chunk (tid&7)
  const int srw = tid >> 3, stc = tid & 7;
  u32x4 kreg0, kreg1, vreg0, vreg1;

  auto load_tiles = [&](int kv0) {
    const bf16* kp = kh + (rowbase + kv0 + srw) * DMODEL + h * 64 + stc * 8;
    kreg0 = *(const u32x4*)kp;
    kreg1 = *(const u32x4*)(kp + 32 * DMODEL);
    const bf16* vp = vt + ((size_t)bh * 64 + srw) * SEQ + kv0 + stc * 8;
    vreg0 = *(const u32x4*)vp;
    vreg1 = *(const u32x4*)(vp + 32 * SEQ);
  };
  auto write_tiles = [&](int buf) {
    char* Kb = (char*)Kls[buf];
    char* Vb = (char*)Vls[buf];
    const int off0 = srw * 128 + ((stc * 16) ^ ((srw & 7) << 4));
    *(u32x4*)(Kb + off0)        = kreg0;
    *(u32x4*)(Kb + off0 + 4096) = kreg1;   // row+32: same &7 -> same swizzle
    *(u32x4*)(Vb + off0)        = vreg0;
    *(u32x4*)(Vb + off0 + 4096) = vreg1;
  };

  load_tiles(0);
  write_tiles(0);
  int cur = 0;
  const int NT = SEQ / 64;

  for (int t = 0; t < NT; ++t) {
    __syncthreads();                       // LDS[cur] ready; LDS[cur^1] free
    if (t + 1 < NT) load_tiles((t + 1) * 64);

    const char* Kb = (const char*)Kls[cur];
    const char* Vb = (const char*)Vls[cur];

    // ---- QK^T swapped: s[n][r] = S^T[kv = n*16+g*4+r][q = c] ----
    f32x4 s[4] = {};
    #pragma unroll
    for (int n = 0; n < 4; ++n) {
      const int row = n * 16 + c;
      const int sw = (row & 7) << 4;
      bf16x8 k0 = *(const bf16x8*)(Kb + row * 128 + ((g * 16     ) ^ sw));
      bf16x8 k1 = *(const bf16x8*)(Kb + row * 128 + ((g * 16 + 64) ^ sw));
      s[n] = __builtin_amdgcn_mfma_f32_16x16x32_bf16(k0, qf0, s[n], 0, 0, 0);
      s[n] = __builtin_amdgcn_mfma_f32_16x16x32_bf16(k1, qf1, s[n], 0, 0, 0);
    }

    // ---- online softmax over kv (in-lane 16 + 2 shfls across g) ----
    float mt = s[0][0];
    #pragma unroll
    for (int n = 0; n < 4; ++n)
      #pragma unroll
      for (int r = 0; r < 4; ++r) mt = fmaxf(mt, s[n][r]);
    mt = fmaxf(mt, __shfl_xor(mt, 16));
    mt = fmaxf(mt, __shfl_xor(mt, 32));
    const float mnew = fmaxf(mrun, mt);
    const float alpha = __expf(mrun - mnew);
    mrun = mnew;
    float ps = 0.f;
    #pragma unroll
    for (int n = 0; n < 4; ++n)
      #pragma unroll
      for (int r = 0; r < 4; ++r) {
        float p = __expf(s[n][r] - mnew);
        s[n][r] = p; ps += p;
      }
    ps += __shfl_xor(ps, 16);
    ps += __shfl_xor(ps, 32);
    lrun = lrun * alpha + ps;
    #pragma unroll
    for (int m4 = 0; m4 < 4; ++m4) oacc[m4] *= alpha;

    // ---- pack P^T to bf16 pairs: pk[n][rp] = (kv=n*16+g*4+2rp, +1) @ q=c ----
    unsigned int pk[4][2];
    #pragma unroll
    for (int n = 0; n < 4; ++n) {
      pk[n][0] = packbf2(s[n][0], s[n][1]);
      pk[n][1] = packbf2(s[n][2], s[n][3]);
    }

    // ---- assemble PV B-operand: lane (c,g) needs P^T[kv=ks*32+g*8+j][q=c] ----
    union U8 { unsigned int u[4]; bf16x8 v; } pf0, pf1;
    const int base = c + 32 * (g & 1);
    const int sel = g >> 1;
    #pragma unroll
    for (int w = 0; w < 4; ++w) {
      const int sl = base + 16 * (w >> 1);
      unsigned int a0 = (unsigned int)__shfl((int)pk[0][w & 1], sl);
      unsigned int a1 = (unsigned int)__shfl((int)pk[1][w & 1], sl);
      pf0.u[w] = sel ? a1 : a0;
      unsigned int b0 = (unsigned int)__shfl((int)pk[2][w & 1], sl);
      unsigned int b1 = (unsigned int)__shfl((int)pk[3][w & 1], sl);
      pf1.u[w] = sel ? b1 : b0;
    }

    // ---- PV: O^T[d][q] += V^T[d][kv] * P^T[kv][q] ----
    #pragma unroll
    for (int m4 = 0; m4 < 4; ++m4) {
      const int row = m4 * 16 + c;
      const int sw = (row & 7) << 4;
      bf16x8 v0 = *(const bf16x8*)(Vb + row * 128 + ((g * 16     ) ^ sw));
      bf16x8 v1 = *(const bf16x8*)(Vb + row * 128 + ((g * 16 + 64) ^ sw));
      oacc[m4] = __builtin_amdgcn_mfma_f32_16x16x32_bf16(v0, pf0.v, oacc[m4], 0, 0, 0);
      oacc[m4] = __builtin_amdgcn_mfma_f32_16x16x32_bf16(v1, pf1.v, oacc[m4], 0, 0, 0);
    }

    if (t + 1 < NT) write_tiles(cur ^ 1);
    cur ^= 1;
  }

  // ---- epilogue: O^T/l -> ao[q][d], packed b64 stores ----
  const float inv = 1.f / lrun;
  bf16* dst = ao + (rowbase + q0 + wave * 16 + c) * DMODEL + h * 64;
  #pragma unroll
  for (int m4 = 0; m4 < 4; ++m4) {
    u32x2 pkd;
    pkd[0] = packbf2(oacc[m4][0] * inv, oacc[m4][1] * inv);
    pkd[1] = packbf2(oacc[m4][2] * inv, oacc[m4][3] * inv);
    *(u32x2*)(dst + m4 * 16 + g * 4) = pkd;
  }
}

// ---------------- host ----------------
extern "C" void kernel_launch(void* const* d_in, const int* in_sizes, int n_in,
                              void* d_out, int out_size, void* d_ws, size_t ws_size,
                              hipStream_t stream) {
  const float* q  = (const float*)d_in[0];
  const float* k  = (const float*)d_in[1];
  const float* v  = (const float*)d_in[2];
  const float* Wq = (const float*)d_in[3];
  const float* bq = (const float*)d_in[4];
  const float* Wk = (const float*)d_in[5];
  const float* bk = (const float*)d_in[6];
  const float* Wv = (const float*)d_in[7];
  const float* bv = (const float*)d_in[8];
  const float* Wo = (const float*)d_in[9];
  const float* bo = (const float*)d_in[10];
  float* out = (float*)d_out;

  char* w = (char*)d_ws;
  bf16* qb  = (bf16*)w; w += (size_t)BSD * 2;
  bf16* kb  = (bf16*)w; w += (size_t)BSD * 2;
  bf16* vb  = (bf16*)w; w += (size_t)BSD * 2;
  bf16* Wqb = (bf16*)w; w += (size_t)DD * 2;
  bf16* Wkb = (bf16*)w; w += (size_t)DD * 2;
  bf16* Wvb = (bf16*)w; w += (size_t)DD * 2;
  bf16* Wob = (bf16*)w; w += (size_t)DD * 2;
  bf16* qhd = (bf16*)w; w += (size_t)BSD * 2;
  bf16* khd = (bf16*)w; w += (size_t)BSD * 2;
  bf16* vtd = (bf16*)w; w += (size_t)BSD * 2;   // V^T: [(b*16+h)*64+dk][2048]
  bf16* aod = (bf16*)w; w += (size_t)BSD * 2;

  cvt_kernel<<<BSD / 8 / 256, 256, 0, stream>>>(q, qb, BSD / 8);
  cvt_kernel<<<BSD / 8 / 256, 256, 0, stream>>>(k, kb, BSD / 8);
  cvt_kernel<<<BSD / 8 / 256, 256, 0, stream>>>(v, vb, BSD / 8);
  cvt_kernel<<<DD  / 8 / 256, 256, 0, stream>>>(Wq, Wqb, DD / 8);
  cvt_kernel<<<DD  / 8 / 256, 256, 0, stream>>>(Wk, Wkb, DD / 8);
  cvt_kernel<<<DD  / 8 / 256, 256, 0, stream>>>(Wv, Wvb, DD / 8);
  cvt_kernel<<<DD  / 8 / 256, 256, 0, stream>>>(Wo, Wob, DD / 8);

  gemm_qk_kernel<<<dim3(8, 32, 2), 256, 0, stream>>>(qb, kb, Wqb, Wkb, bq, bk, qhd, khd);
  gemm_v_kernel<<<dim3(8, 32), 256, 0, stream>>>(vb, Wvb, bv, vtd);
  attn_kernel<<<1024, 256, 0, stream>>>(qhd, khd, vtd, aod);
  gemm_out_kernel<<<dim3(8, 32), 256, 0, stream>>>(aod, Wob, bo, out);
}